// Round 1
// baseline (460.209 us; speedup 1.0000x reference)
//
#include <hip/hip_runtime.h>
#include <math.h>

#define SLEN 4096
#define DH   64
#define QBLK 64
#define KVB  64
#define KPAD 72   // LDS row stride in bf16 elems (144 B) -> 2-way bank alias only

typedef float f32x4 __attribute__((ext_vector_type(4)));
typedef short bf16x8 __attribute__((ext_vector_type(8)));      // 8 bf16 in 4 VGPRs
typedef unsigned short u16x8 __attribute__((ext_vector_type(8)));

union U8 { u16x8 u; bf16x8 b; };

__device__ inline unsigned short f2bf(float f) {
    unsigned int u = __builtin_bit_cast(unsigned int, f);
    u += 0x7FFFu + ((u >> 16) & 1u);   // RNE
    return (unsigned short)(u >> 16);
}

extern "C" __global__ __launch_bounds__(256)
void fa_fwd_causal(const float* __restrict__ Q, const float* __restrict__ K,
                   const float* __restrict__ V, float* __restrict__ O)
{
    const int tid  = threadIdx.x;
    const int lane = tid & 63;
    const int w    = tid >> 6;          // wave id 0..3
    const int l15  = lane & 15;
    const int l4   = lane >> 4;

    const int qtile = blockIdx.x;       // 0..63
    const int head  = blockIdx.y;       // 0..31  (b*16+h)
    const int q0    = qtile * QBLK;
    const size_t base = (size_t)head * SLEN * DH;

    __shared__ unsigned short Kl[KVB * KPAD];     // K tile, row-major [kk][d]
    __shared__ unsigned short Vt[DH * KPAD];      // V tile transposed [d][kk]
    __shared__ unsigned short Pl[4][16 * KPAD];   // per-wave P staging [q][kk]

    // ---- Q fragments (scaled by 1/sqrt(D)=0.125, exact in bf16) ----
    bf16x8 aq[2];
    {
        const int qr = q0 + w * 16 + l15;
        const float* qp = Q + base + (size_t)qr * DH + l4 * 8;
        #pragma unroll
        for (int ch = 0; ch < 2; ++ch) {
            float4 f0 = *(const float4*)(qp + ch * 32);
            float4 f1 = *(const float4*)(qp + ch * 32 + 4);
            U8 u;
            u.u[0] = f2bf(f0.x * 0.125f); u.u[1] = f2bf(f0.y * 0.125f);
            u.u[2] = f2bf(f0.z * 0.125f); u.u[3] = f2bf(f0.w * 0.125f);
            u.u[4] = f2bf(f1.x * 0.125f); u.u[5] = f2bf(f1.y * 0.125f);
            u.u[6] = f2bf(f1.z * 0.125f); u.u[7] = f2bf(f1.w * 0.125f);
            aq[ch] = u.b;
        }
    }

    f32x4 acc[4] = {};                  // O accumulator, 4 N-tiles over D
    float mrun[4], lrun[4];
    #pragma unroll
    for (int r = 0; r < 4; ++r) { mrun[r] = -INFINITY; lrun[r] = 0.f; }

    const int ntiles = qtile + 1;       // causal: only up to diagonal
    for (int t = 0; t < ntiles; ++t) {
        const int k0 = t * KVB;
        __syncthreads();                // previous tile's LDS reads done

        // ---- stage K (row-major) and V (transposed) into LDS as bf16 ----
        {
            const int row = tid >> 2;           // 0..63
            const int c0  = (tid & 3) * 16;     // 0,16,32,48
            const float* kp = K + base + (size_t)(k0 + row) * DH + c0;
            unsigned short tmp[16];
            #pragma unroll
            for (int i = 0; i < 4; ++i) {
                float4 f = *(const float4*)(kp + i * 4);
                tmp[i*4+0] = f2bf(f.x); tmp[i*4+1] = f2bf(f.y);
                tmp[i*4+2] = f2bf(f.z); tmp[i*4+3] = f2bf(f.w);
            }
            unsigned short* dst = &Kl[row * KPAD + c0];
            *(u16x8*)dst       = *(u16x8*)tmp;
            *(u16x8*)(dst + 8) = *(u16x8*)(tmp + 8);

            const float* vp = V + base + (size_t)(k0 + row) * DH + c0;
            #pragma unroll
            for (int i = 0; i < 4; ++i) {
                float4 f = *(const float4*)(vp + i * 4);
                Vt[(c0 + i*4 + 0) * KPAD + row] = f2bf(f.x);
                Vt[(c0 + i*4 + 1) * KPAD + row] = f2bf(f.y);
                Vt[(c0 + i*4 + 2) * KPAD + row] = f2bf(f.z);
                Vt[(c0 + i*4 + 3) * KPAD + row] = f2bf(f.w);
            }
        }
        __syncthreads();

        // ---- QK^T: scores s[nt] covers cols k0+nt*16+l15, rows q0+w*16+(l4*4+r) ----
        f32x4 s[4];
        #pragma unroll
        for (int nt = 0; nt < 4; ++nt) {
            f32x4 a = {};
            #pragma unroll
            for (int ch = 0; ch < 2; ++ch) {
                U8 bk;
                bk.u = *(const u16x8*)&Kl[(nt*16 + l15) * KPAD + ch*32 + l4*8];
                a = __builtin_amdgcn_mfma_f32_16x16x32_bf16(aq[ch], bk.b, a, 0, 0, 0);
            }
            s[nt] = a;
        }

        // ---- causal mask (only when tile overlaps diagonal for this wave) ----
        const int rowbase = q0 + w * 16 + l4 * 4;
        if (k0 + KVB - 1 > q0 + w * 16) {
            #pragma unroll
            for (int nt = 0; nt < 4; ++nt) {
                const int kc = k0 + nt * 16 + l15;
                #pragma unroll
                for (int r = 0; r < 4; ++r)
                    if (kc > rowbase + r) s[nt][r] = -INFINITY;
            }
        }

        // ---- online softmax (per row r; 16 lanes share a row) ----
        float pr[4][4];
        #pragma unroll
        for (int r = 0; r < 4; ++r) {
            float mx = fmaxf(fmaxf(s[0][r], s[1][r]), fmaxf(s[2][r], s[3][r]));
            #pragma unroll
            for (int off = 1; off < 16; off <<= 1)
                mx = fmaxf(mx, __shfl_xor(mx, off));
            float mn = fmaxf(mrun[r], mx);
            float fr = __expf(mrun[r] - mn);
            mrun[r] = mn;
            float rs = 0.f;
            #pragma unroll
            for (int nt = 0; nt < 4; ++nt) {
                float p = __expf(s[nt][r] - mn);
                pr[nt][r] = p;
                rs += p;
            }
            #pragma unroll
            for (int off = 1; off < 16; off <<= 1)
                rs += __shfl_xor(rs, off);
            lrun[r] = lrun[r] * fr + rs;
            #pragma unroll
            for (int nt = 0; nt < 4; ++nt) acc[nt][r] *= fr;
        }

        // ---- write P (C-layout) to per-wave LDS, reread in A-layout ----
        unsigned short* Pw = Pl[w];
        #pragma unroll
        for (int r = 0; r < 4; ++r)
            #pragma unroll
            for (int nt = 0; nt < 4; ++nt)
                Pw[(l4*4 + r) * KPAD + nt*16 + l15] = f2bf(pr[nt][r]);

        asm volatile("s_waitcnt lgkmcnt(0)" ::: "memory");   // cross-lane RAW in wave

        // ---- PV: acc[ntD] += P(16x64) @ V(64x16) ----
        U8 pa0, pa1;
        pa0.u = *(const u16x8*)&Pw[l15 * KPAD + l4*8];
        pa1.u = *(const u16x8*)&Pw[l15 * KPAD + 32 + l4*8];
        #pragma unroll
        for (int nt = 0; nt < 4; ++nt) {
            U8 vb0, vb1;
            vb0.u = *(const u16x8*)&Vt[(nt*16 + l15) * KPAD + l4*8];
            vb1.u = *(const u16x8*)&Vt[(nt*16 + l15) * KPAD + 32 + l4*8];
            acc[nt] = __builtin_amdgcn_mfma_f32_16x16x32_bf16(pa0.b, vb0.b, acc[nt], 0, 0, 0);
            acc[nt] = __builtin_amdgcn_mfma_f32_16x16x32_bf16(pa1.b, vb1.b, acc[nt], 0, 0, 0);
        }
    }

    // ---- epilogue: O = acc / l ----
    const int rowb = q0 + w * 16 + l4 * 4;
    #pragma unroll
    for (int r = 0; r < 4; ++r) {
        float inv = 1.f / lrun[r];
        float* op = O + base + (size_t)(rowb + r) * DH + l15;
        #pragma unroll
        for (int nt = 0; nt < 4; ++nt)
            op[nt * 16] = acc[nt][r] * inv;
    }
}

extern "C" void kernel_launch(void* const* d_in, const int* in_sizes, int n_in,
                              void* d_out, int out_size, void* d_ws, size_t ws_size,
                              hipStream_t stream) {
    (void)in_sizes; (void)n_in; (void)d_ws; (void)ws_size; (void)out_size;
    const float* q = (const float*)d_in[0];
    const float* k = (const float*)d_in[1];
    const float* v = (const float*)d_in[2];
    // d_in[3] is the causal mask; causality is hardcoded in the kernel.
    float* o = (float*)d_out;
    dim3 grid(SLEN / QBLK, 2 * 16);   // (64 q-tiles, B*H heads)
    dim3 block(256);
    fa_fwd_causal<<<grid, block, 0, stream>>>(q, k, v, o);
}

// Round 3
// 406.302 us; speedup vs baseline: 1.1327x; 1.1327x over previous
//
#include <hip/hip_runtime.h>
#include <hip/hip_bf16.h>
#include <math.h>

#define SLEN 4096
#define DH   64
#define QBLK 128
#define KVB  64
#define KPAD 72   // LDS row stride in bf16 elems (144 B)

typedef float f32x4 __attribute__((ext_vector_type(4)));
typedef short bf16x8 __attribute__((ext_vector_type(8)));
typedef unsigned short u16x8 __attribute__((ext_vector_type(8)));
typedef unsigned short u16x4 __attribute__((ext_vector_type(4)));

union U8 { u16x8 u; bf16x8 b; };

__device__ inline unsigned short f2bf(float f) {
    return __builtin_bit_cast(unsigned short, __float2bfloat16(f));
}

extern "C" __global__ __launch_bounds__(256)
void fa_fwd_causal(const float* __restrict__ Q, const float* __restrict__ K,
                   const float* __restrict__ V, float* __restrict__ O)
{
    const int tid  = threadIdx.x;
    const int lane = tid & 63;
    const int w    = tid >> 6;          // wave id 0..3
    const int l15  = lane & 15;
    const int l4   = lane >> 4;

    const int qtile = (int)gridDim.x - 1 - (int)blockIdx.x;  // heavy blocks first
    const int head  = blockIdx.y;
    const int q0    = qtile * QBLK;
    const size_t base = (size_t)head * SLEN * DH;

    __shared__ unsigned short Kl[KVB * KPAD];      // K tile row-major [kk][d]
    __shared__ unsigned short Vt[DH * KPAD];       // V tile transposed [d][kk]
    __shared__ unsigned short Pl[4][2][16 * KPAD]; // per-wave,set P [q][kk]

    // Q scale folds 1/sqrt(D) and log2(e): softmax runs in exp2 domain.
    const float QSC = 0.125f * 1.44269504088896340736f;

    // ---- Q fragments: B-operand, lane reads Q[q=l15][d-run] ----
    bf16x8 aq[2][2];
    #pragma unroll
    for (int set = 0; set < 2; ++set) {
        const int qr = q0 + w * 32 + set * 16 + l15;
        const float* qp = Q + base + (size_t)qr * DH + l4 * 8;
        #pragma unroll
        for (int ch = 0; ch < 2; ++ch) {
            float4 f0 = *(const float4*)(qp + ch * 32);
            float4 f1 = *(const float4*)(qp + ch * 32 + 4);
            U8 u;
            u.u[0] = f2bf(f0.x * QSC); u.u[1] = f2bf(f0.y * QSC);
            u.u[2] = f2bf(f0.z * QSC); u.u[3] = f2bf(f0.w * QSC);
            u.u[4] = f2bf(f1.x * QSC); u.u[5] = f2bf(f1.y * QSC);
            u.u[6] = f2bf(f1.z * QSC); u.u[7] = f2bf(f1.w * QSC);
            aq[set][ch] = u.b;
        }
    }

    f32x4 acc[2][4] = {};               // O acc: rows q=qs0+l4*4+r, cols d=nt*16+l15
    float mrun[2] = { -INFINITY, -INFINITY };
    float lrun[2] = { 0.f, 0.f };

    const int ntiles = 2 * qtile + 2;
    for (int t = 0; t < ntiles; ++t) {
        const int k0 = t * KVB;
        __syncthreads();

        // ---- stage K (row-major) and V (transposed) as bf16 ----
        {
            const int row = tid >> 2;
            const int c0  = (tid & 3) * 16;
            const float* kp = K + base + (size_t)(k0 + row) * DH + c0;
            unsigned short tmp[16];
            #pragma unroll
            for (int i = 0; i < 4; ++i) {
                float4 f = *(const float4*)(kp + i * 4);
                tmp[i*4+0] = f2bf(f.x); tmp[i*4+1] = f2bf(f.y);
                tmp[i*4+2] = f2bf(f.z); tmp[i*4+3] = f2bf(f.w);
            }
            unsigned short* dst = &Kl[row * KPAD + c0];
            *(u16x8*)dst       = *(u16x8*)tmp;
            *(u16x8*)(dst + 8) = *(u16x8*)(tmp + 8);

            const float* vp = V + base + (size_t)(k0 + row) * DH + c0;
            #pragma unroll
            for (int i = 0; i < 4; ++i) {
                float4 f = *(const float4*)(vp + i * 4);
                Vt[(c0 + i*4 + 0) * KPAD + row] = f2bf(f.x);
                Vt[(c0 + i*4 + 1) * KPAD + row] = f2bf(f.y);
                Vt[(c0 + i*4 + 2) * KPAD + row] = f2bf(f.z);
                Vt[(c0 + i*4 + 3) * KPAD + row] = f2bf(f.w);
            }
        }
        __syncthreads();

        const int qwave = q0 + w * 32;
        if (k0 <= qwave + 31) {          // wave-uniform: any unmasked work
            #pragma unroll
            for (int set = 0; set < 2; ++set) {
                const int qs0 = qwave + set * 16;
                if (k0 > qs0 + 15) continue;      // fully masked for this set
                const int q = qs0 + l15;

                // ---- swapped QK^T: D[kk][q], row=kk=l4*4+r, col=q=l15 ----
                f32x4 s[4];
                #pragma unroll
                for (int nt = 0; nt < 4; ++nt) {
                    U8 ak0, ak1;
                    ak0.u = *(const u16x8*)&Kl[(nt*16 + l15) * KPAD + l4*8];
                    ak1.u = *(const u16x8*)&Kl[(nt*16 + l15) * KPAD + 32 + l4*8];
                    f32x4 z = {};
                    z = __builtin_amdgcn_mfma_f32_16x16x32_bf16(ak0.b, aq[set][0], z, 0, 0, 0);
                    z = __builtin_amdgcn_mfma_f32_16x16x32_bf16(ak1.b, aq[set][1], z, 0, 0, 0);
                    s[nt] = z;
                }

                if (k0 + KVB - 1 > qs0) {
                    #pragma unroll
                    for (int nt = 0; nt < 4; ++nt)
                        #pragma unroll
                        for (int r = 0; r < 4; ++r)
                            if (k0 + nt*16 + l4*4 + r > q) s[nt][r] = -INFINITY;
                }

                // ---- softmax: lane owns q=l15's 16 kk-partials; 2-shfl reduce ----
                float mx = s[0][0];
                #pragma unroll
                for (int nt = 0; nt < 4; ++nt)
                    #pragma unroll
                    for (int r = 0; r < 4; ++r)
                        if (!(nt == 0 && r == 0)) mx = fmaxf(mx, s[nt][r]);
                mx = fmaxf(mx, __shfl_xor(mx, 16));
                mx = fmaxf(mx, __shfl_xor(mx, 32));
                float mn = fmaxf(mrun[set], mx);
                float fr = exp2f(mrun[set] - mn);
                mrun[set] = mn;

                float p[4][4];
                float rs = 0.f;
                #pragma unroll
                for (int nt = 0; nt < 4; ++nt)
                    #pragma unroll
                    for (int r = 0; r < 4; ++r) {
                        float e = exp2f(s[nt][r] - mn);
                        p[nt][r] = e;
                        rs += e;
                    }
                rs += __shfl_xor(rs, 16);
                rs += __shfl_xor(rs, 32);
                lrun[set] = lrun[set] * fr + rs;

                // ---- P store: 4 contiguous kk per lane -> b64 stores ----
                unsigned short* Pw = &Pl[w][set][0];
                #pragma unroll
                for (int nt = 0; nt < 4; ++nt) {
                    u16x4 pk;
                    pk[0] = f2bf(p[nt][0]); pk[1] = f2bf(p[nt][1]);
                    pk[2] = f2bf(p[nt][2]); pk[3] = f2bf(p[nt][3]);
                    *(u16x4*)&Pw[l15 * KPAD + nt*16 + l4*4] = pk;
                }

                // ---- rescale acc (fr redistributed to acc row layout) ----
                #pragma unroll
                for (int r = 0; r < 4; ++r) {
                    float frr = __shfl(fr, l4*4 + r);
                    #pragma unroll
                    for (int nt = 0; nt < 4; ++nt) acc[set][nt][r] *= frr;
                }

                asm volatile("s_waitcnt lgkmcnt(0)" ::: "memory");
                __builtin_amdgcn_sched_barrier(0);

                // ---- PV: acc += P(16q x 64kk) @ V(64kk x 64d) ----
                U8 pa0, pa1;
                pa0.u = *(const u16x8*)&Pw[l15 * KPAD + l4*8];
                pa1.u = *(const u16x8*)&Pw[l15 * KPAD + 32 + l4*8];
                #pragma unroll
                for (int nt = 0; nt < 4; ++nt) {
                    U8 vb0, vb1;
                    vb0.u = *(const u16x8*)&Vt[(nt*16 + l15) * KPAD + l4*8];
                    vb1.u = *(const u16x8*)&Vt[(nt*16 + l15) * KPAD + 32 + l4*8];
                    acc[set][nt] = __builtin_amdgcn_mfma_f32_16x16x32_bf16(pa0.b, vb0.b, acc[set][nt], 0, 0, 0);
                    acc[set][nt] = __builtin_amdgcn_mfma_f32_16x16x32_bf16(pa1.b, vb1.b, acc[set][nt], 0, 0, 0);
                }
            }
        }
    }

    // ---- epilogue: O = acc / l (inv redistributed to acc row layout) ----
    #pragma unroll
    for (int set = 0; set < 2; ++set) {
        float inv = 1.f / lrun[set];
        #pragma unroll
        for (int r = 0; r < 4; ++r) {
            float invr = __shfl(inv, l4*4 + r);
            const int qrow = q0 + w*32 + set*16 + l4*4 + r;
            float* op = O + base + (size_t)qrow * DH + l15;
            #pragma unroll
            for (int nt = 0; nt < 4; ++nt)
                op[nt*16] = acc[set][nt][r] * invr;
        }
    }
}

extern "C" void kernel_launch(void* const* d_in, const int* in_sizes, int n_in,
                              void* d_out, int out_size, void* d_ws, size_t ws_size,
                              hipStream_t stream) {
    (void)in_sizes; (void)n_in; (void)d_ws; (void)ws_size; (void)out_size;
    const float* q = (const float*)d_in[0];
    const float* k = (const float*)d_in[1];
    const float* v = (const float*)d_in[2];
    float* o = (float*)d_out;
    dim3 grid(SLEN / QBLK, 2 * 16);
    dim3 block(256);
    fa_fwd_causal<<<grid, block, 0, stream>>>(q, k, v, o);
}

// Round 4
// 204.450 us; speedup vs baseline: 2.2510x; 1.9873x over previous
//
#include <hip/hip_runtime.h>
#include <hip/hip_bf16.h>
#include <math.h>

#define SLEN 4096
#define DH   64
#define QBLK 128
#define KVB  64
#define KPAD 72
#define NQT  (SLEN/QBLK)   // 32
#define NPAIR (NQT/2)      // 16
#define NHEAD 32

typedef float  f32x4 __attribute__((ext_vector_type(4)));
typedef short  bf16x8 __attribute__((ext_vector_type(8)));
typedef unsigned short u16x8 __attribute__((ext_vector_type(8)));
typedef unsigned short u16x4 __attribute__((ext_vector_type(4)));
union U8 { u16x8 u; bf16x8 b; };

__device__ inline unsigned short f2bf(float f) {
    return __builtin_bit_cast(unsigned short, __float2bfloat16(f));
}

extern "C" __global__ __launch_bounds__(256)
void fa_fwd_causal(const float* __restrict__ Q, const float* __restrict__ K,
                   const float* __restrict__ V, float* __restrict__ O)
{
    const int tid  = threadIdx.x;
    const int lane = tid & 63;
    const int w    = tid >> 6;
    const int l15  = lane & 15;
    const int l4   = lane >> 4;

    // 512 blocks; XCD-chunked swizzle (512%8==0 -> bijective): XCD c -> heads 4c..4c+3
    const int bid  = (int)blockIdx.x;
    const int work = (bid & 7) * (NPAIR * NHEAD / 8) + (bid >> 3);
    const int head = work >> 4;           // work / NPAIR
    const int pr   = work & (NPAIR - 1);  // pair index 0..15
    const size_t base = (size_t)head * SLEN * DH;

    __shared__ unsigned short Kl[2][KVB * KPAD];   // K tile row-major [kk][d], dbuf
    __shared__ unsigned short Vt[2][DH * KPAD];    // V tile transposed [d][kk], dbuf
    __shared__ unsigned short Plds[4][16 * KPAD];  // per-wave P staging (shared by sets)

    const float QSC = 0.125f * 1.44269504088896340736f;  // 1/sqrt(64) * log2(e)

    const int krow = tid >> 2,        kc0 = (tid & 3) * 16;   // K staging coords
    const int vd0  = (tid >> 4) * 4,  vk0 = (tid & 15) * 4;   // V staging coords

    #pragma unroll 1
    for (int ph = 0; ph < 2; ++ph) {
        const int qt  = ph ? (NQT - 1 - pr) : pr;   // light tile, then heavy tile
        const int q0  = qt * QBLK;
        const int ntl = 2 * qt + 2;                  // KV tiles up to diagonal
        const int qwave = q0 + w * 32;

        // ---- Q fragments (B-operand; lane reads Q[q=l15][d-run]) ----
        bf16x8 aq[2][2];
        #pragma unroll
        for (int set = 0; set < 2; ++set) {
            const int qr = q0 + w * 32 + set * 16 + l15;
            const float* qp = Q + base + (size_t)qr * DH + l4 * 8;
            #pragma unroll
            for (int ch = 0; ch < 2; ++ch) {
                f32x4 f0 = *(const f32x4*)(qp + ch * 32);
                f32x4 f1 = *(const f32x4*)(qp + ch * 32 + 4);
                U8 u;
                #pragma unroll
                for (int j = 0; j < 4; ++j) { u.u[j] = f2bf(f0[j] * QSC); u.u[4 + j] = f2bf(f1[j] * QSC); }
                aq[set][ch] = u.b;
            }
        }

        f32x4 acc[2][4] = {};
        float mrun[2] = { -INFINITY, -INFINITY };
        float lrun[2] = { 0.f, 0.f };

        f32x4 kreg[4], vreg[4];   // in-flight next-tile data (register prefetch)

        auto g_load = [&](int t) {
            const float* kp = K + base + (size_t)(t * KVB + krow) * DH + kc0;
            #pragma unroll
            for (int i = 0; i < 4; ++i) kreg[i] = *(const f32x4*)(kp + i * 4);
            const float* vp = V + base + (size_t)(t * KVB + vk0) * DH + vd0;
            #pragma unroll
            for (int i = 0; i < 4; ++i) vreg[i] = *(const f32x4*)(vp + (size_t)i * DH);
        };
        auto s_write = [&](int c) {
            unsigned short tmp[16];
            #pragma unroll
            for (int i = 0; i < 4; ++i)
                #pragma unroll
                for (int j = 0; j < 4; ++j) tmp[i * 4 + j] = f2bf(kreg[i][j]);
            unsigned short* kd = &Kl[c][krow * KPAD + kc0];
            *(u16x8*)kd       = *(u16x8*)&tmp[0];
            *(u16x8*)(kd + 8) = *(u16x8*)&tmp[8];
            #pragma unroll
            for (int i = 0; i < 4; ++i) {      // transposed V write: 4 kk per b64
                u16x4 pk;
                pk[0] = f2bf(vreg[0][i]); pk[1] = f2bf(vreg[1][i]);
                pk[2] = f2bf(vreg[2][i]); pk[3] = f2bf(vreg[3][i]);
                *(u16x4*)&Vt[c][(vd0 + i) * KPAD + vk0] = pk;
            }
        };

        // pipeline prologue: tile0 -> LDS buf0, tile1 -> regs
        g_load(0);
        s_write(0);
        g_load(1);
        __syncthreads();

        for (int t = 0; t < ntl; ++t) {
            const int c  = t & 1;
            const int k0 = t * KVB;

            // stage tile t+1 into other buffer; prefetch t+2 into regs
            if (t + 1 < ntl) {
                s_write(c ^ 1);
                if (t + 2 < ntl) g_load(t + 2);
            }

            if (k0 <= qwave + 31) {
                #pragma unroll
                for (int set = 0; set < 2; ++set) {
                    const int qs0 = qwave + set * 16;
                    if (k0 > qs0 + 15) continue;       // fully masked for this set
                    const int q = qs0 + l15;

                    // swapped QK^T: D[kk][q], lane owns q-column
                    f32x4 s[4];
                    #pragma unroll
                    for (int nt = 0; nt < 4; ++nt) {
                        U8 ak0, ak1;
                        ak0.u = *(const u16x8*)&Kl[c][(nt*16 + l15) * KPAD + l4*8];
                        ak1.u = *(const u16x8*)&Kl[c][(nt*16 + l15) * KPAD + 32 + l4*8];
                        f32x4 z = {};
                        z = __builtin_amdgcn_mfma_f32_16x16x32_bf16(ak0.b, aq[set][0], z, 0, 0, 0);
                        z = __builtin_amdgcn_mfma_f32_16x16x32_bf16(ak1.b, aq[set][1], z, 0, 0, 0);
                        s[nt] = z;
                    }

                    if (k0 + KVB - 1 > qs0) {
                        #pragma unroll
                        for (int nt = 0; nt < 4; ++nt)
                            #pragma unroll
                            for (int r = 0; r < 4; ++r)
                                if (k0 + nt*16 + l4*4 + r > q) s[nt][r] = -INFINITY;
                    }

                    // softmax: 15 in-lane fmax + 2 shfl
                    float mx = s[0][0];
                    #pragma unroll
                    for (int nt = 0; nt < 4; ++nt)
                        #pragma unroll
                        for (int r = 0; r < 4; ++r)
                            if (!(nt == 0 && r == 0)) mx = fmaxf(mx, s[nt][r]);
                    mx = fmaxf(mx, __shfl_xor(mx, 16));
                    mx = fmaxf(mx, __shfl_xor(mx, 32));
                    float mn = fmaxf(mrun[set], mx);
                    float fr = exp2f(mrun[set] - mn);
                    mrun[set] = mn;

                    float p[4][4];
                    float rs = 0.f;
                    #pragma unroll
                    for (int nt = 0; nt < 4; ++nt)
                        #pragma unroll
                        for (int r = 0; r < 4; ++r) {
                            float e = exp2f(s[nt][r] - mn);
                            p[nt][r] = e;
                            rs += e;
                        }
                    rs += __shfl_xor(rs, 16);
                    rs += __shfl_xor(rs, 32);
                    lrun[set] = lrun[set] * fr + rs;

                    // P C-layout -> A-layout via per-wave LDS (b64 stores)
                    unsigned short* Pw = &Plds[w][0];
                    #pragma unroll
                    for (int nt = 0; nt < 4; ++nt) {
                        u16x4 pk;
                        pk[0] = f2bf(p[nt][0]); pk[1] = f2bf(p[nt][1]);
                        pk[2] = f2bf(p[nt][2]); pk[3] = f2bf(p[nt][3]);
                        *(u16x4*)&Pw[l15 * KPAD + nt*16 + l4*4] = pk;
                    }

                    // rescale acc by fr (redistributed to acc row layout)
                    #pragma unroll
                    for (int r = 0; r < 4; ++r) {
                        float frr = __shfl(fr, l4*4 + r);
                        #pragma unroll
                        for (int nt = 0; nt < 4; ++nt) acc[set][nt][r] *= frr;
                    }

                    asm volatile("s_waitcnt lgkmcnt(0)" ::: "memory");
                    __builtin_amdgcn_sched_barrier(0);

                    // PV: acc += P(16q x 64kk) @ V(64kk x 64d)
                    U8 pa0, pa1;
                    pa0.u = *(const u16x8*)&Pw[l15 * KPAD + l4*8];
                    pa1.u = *(const u16x8*)&Pw[l15 * KPAD + 32 + l4*8];
                    #pragma unroll
                    for (int nt = 0; nt < 4; ++nt) {
                        U8 vb0, vb1;
                        vb0.u = *(const u16x8*)&Vt[c][(nt*16 + l15) * KPAD + l4*8];
                        vb1.u = *(const u16x8*)&Vt[c][(nt*16 + l15) * KPAD + 32 + l4*8];
                        acc[set][nt] = __builtin_amdgcn_mfma_f32_16x16x32_bf16(pa0.b, vb0.b, acc[set][nt], 0, 0, 0);
                        acc[set][nt] = __builtin_amdgcn_mfma_f32_16x16x32_bf16(pa1.b, vb1.b, acc[set][nt], 0, 0, 0);
                    }
                }
            }
            __syncthreads();
        }

        // ---- epilogue: O = acc / l ----
        #pragma unroll
        for (int set = 0; set < 2; ++set) {
            float inv = 1.f / lrun[set];
            #pragma unroll
            for (int r = 0; r < 4; ++r) {
                float invr = __shfl(inv, l4*4 + r);
                const int qrow = q0 + w*32 + set*16 + l4*4 + r;
                float* op = O + base + (size_t)qrow * DH + l15;
                #pragma unroll
                for (int nt = 0; nt < 4; ++nt)
                    op[nt*16] = acc[set][nt][r] * invr;
            }
        }
        __syncthreads();   // protect LDS before next phase's prologue writes
    }
}

extern "C" void kernel_launch(void* const* d_in, const int* in_sizes, int n_in,
                              void* d_out, int out_size, void* d_ws, size_t ws_size,
                              hipStream_t stream) {
    (void)in_sizes; (void)n_in; (void)d_ws; (void)ws_size; (void)out_size;
    const float* q = (const float*)d_in[0];
    const float* k = (const float*)d_in[1];
    const float* v = (const float*)d_in[2];
    float* o = (float*)d_out;
    dim3 grid(NPAIR * NHEAD);   // 512 balanced blocks
    dim3 block(256);
    fa_fwd_causal<<<grid, block, 0, stream>>>(q, k, v, o);
}

// Round 5
// 167.576 us; speedup vs baseline: 2.7463x; 1.2200x over previous
//
#include <hip/hip_runtime.h>
#include <hip/hip_bf16.h>
#include <math.h>

#define SLEN 4096
#define DH   64
#define KVB  64
#define NHEAD 32

typedef float  f32x4 __attribute__((ext_vector_type(4)));
typedef short  bf16x8 __attribute__((ext_vector_type(8)));
typedef unsigned short u16x8 __attribute__((ext_vector_type(8)));
typedef unsigned short u16x4 __attribute__((ext_vector_type(4)));
union U8 { u16x8 u; bf16x8 b; };

__device__ inline unsigned short f2bf(float f) {
    return __builtin_bit_cast(unsigned short, __float2bfloat16(f));
}

__device__ inline void gload16(const unsigned short* g, unsigned short* l) {
    __builtin_amdgcn_global_load_lds(
        (const __attribute__((address_space(1))) void*)g,
        (__attribute__((address_space(3))) void*)l, 16, 0, 0);
}

// ---------------- pre-pass: f32 K,V -> bf16 swizzled tile layout in ws ----------
// Tile layout (4096 bf16 elems): elem index = row*64 + (d ^ ((row&7)<<3)).
// K tiles: row = kv index, d = head dim. V tiles: row = head dim, d = kv (transposed).
extern "C" __global__ __launch_bounds__(512)
void prep_kv(const float* __restrict__ K, const float* __restrict__ V,
             unsigned short* __restrict__ Kb, unsigned short* __restrict__ Vt)
{
    const int tile = blockIdx.x & 63;
    const int head = blockIdx.x >> 6;
    const size_t gbase = (size_t)head * SLEN * DH + (size_t)tile * KVB * DH;
    const size_t tbase = ((size_t)head * 64 + tile) * (KVB * DH);
    const int tid = threadIdx.x;
    if (blockIdx.y == 0) {
        const int row = tid >> 3, d0 = (tid & 7) * 8;
        const float* src = K + gbase + (size_t)row * DH + d0;
        f32x4 a = *(const f32x4*)src, b = *(const f32x4*)(src + 4);
        u16x8 o;
        #pragma unroll
        for (int j = 0; j < 4; ++j) { o[j] = f2bf(a[j]); o[4 + j] = f2bf(b[j]); }
        *(u16x8*)&Kb[tbase + row * 64 + ((unsigned)d0 ^ ((row & 7) << 3))] = o;
    } else {
        const int kk = tid & 63, d0 = (tid >> 6) * 8;
        const float* src = V + gbase + (size_t)kk * DH + d0;
        f32x4 a = *(const f32x4*)src, b = *(const f32x4*)(src + 4);
        #pragma unroll
        for (int j = 0; j < 8; ++j) {
            const int d = d0 + j;
            const float x = (j < 4) ? a[j] : b[j - 4];
            Vt[tbase + d * 64 + ((unsigned)kk ^ ((d & 7) << 3))] = f2bf(x);
        }
    }
}

// ---------------- main kernel: QBLK=64, global_load_lds staging ----------------
#define NQT   (SLEN / KVB)   // 64 q-tiles of 64
#define NPAIR (NQT / 2)      // 32
#define RTHR  10.0f          // defer-max threshold, exp2 domain

extern "C" __global__ __launch_bounds__(256, 4)
void fa_fwd_v5(const float* __restrict__ Q, float* __restrict__ O,
               const unsigned short* __restrict__ Kb,
               const unsigned short* __restrict__ Vt)
{
    const int tid  = threadIdx.x;
    const int lane = tid & 63;
    const int w    = tid >> 6;
    const int l15  = lane & 15;
    const int l4   = lane >> 4;

    // 1024 blocks, XCD-chunked swizzle (1024%8==0 -> bijective)
    const int bid  = (int)blockIdx.x;
    const int work = (bid & 7) * (NPAIR * NHEAD / 8) + (bid >> 3);
    const int head = work >> 5;
    const int pr   = work & (NPAIR - 1);
    const size_t qbase  = (size_t)head * SLEN * DH;
    const size_t kvbase = (size_t)head * 64 * (KVB * DH);   // elem offset into Kb/Vt

    __shared__ __align__(16) unsigned short Kl[2][KVB * DH]; // 8 KB each, swizzled
    __shared__ __align__(16) unsigned short Vl[2][DH * KVB]; // 8 KB each, swizzled
    __shared__ __align__(16) unsigned short Pl[4][16 * 64];  // per-wave P, swizzled

    const float QSC = 0.125f * 1.44269504088896340736f;

    #pragma unroll 1
    for (int ph = 0; ph < 2; ++ph) {
        const int qt  = ph ? (NQT - 1 - pr) : pr;
        const int q0  = qt * KVB;
        const int ntl = qt + 1;
        const int qs0 = q0 + w * 16;
        const int q   = qs0 + l15;

        const unsigned short* ksrc = Kb + kvbase;
        const unsigned short* vsrc = Vt + kvbase;
        auto stage = [&](int c, int t) {
            const size_t toff = (size_t)t * (KVB * DH);
            const int ib = w * 2;                       // wave's 1KB issue blocks
            gload16(ksrc + toff + ib * 512 + lane * 8,       &Kl[c][ib * 512]);
            gload16(ksrc + toff + (ib + 1) * 512 + lane * 8, &Kl[c][(ib + 1) * 512]);
            gload16(vsrc + toff + ib * 512 + lane * 8,       &Vl[c][ib * 512]);
            gload16(vsrc + toff + (ib + 1) * 512 + lane * 8, &Vl[c][(ib + 1) * 512]);
        };

        stage(0, 0);

        // Q fragment (B-operand: lane holds Q[q=l15][d-run]), scaled
        bf16x8 aq[2];
        {
            const float* qp = Q + qbase + (size_t)q * DH + l4 * 8;
            #pragma unroll
            for (int ch = 0; ch < 2; ++ch) {
                f32x4 f0 = *(const f32x4*)(qp + ch * 32);
                f32x4 f1 = *(const f32x4*)(qp + ch * 32 + 4);
                U8 u;
                #pragma unroll
                for (int j = 0; j < 4; ++j) { u.u[j] = f2bf(f0[j] * QSC); u.u[4 + j] = f2bf(f1[j] * QSC); }
                aq[ch] = u.b;
            }
        }

        f32x4 acc[4] = {};
        float mrun = -INFINITY, lrun = 0.f;

        __syncthreads();   // prologue stage(0) complete (compiler drains vmcnt)

        for (int t = 0; t < ntl; ++t) {
            const int c  = t & 1;
            const int k0 = t * KVB;
            if (t + 1 < ntl) stage(c ^ 1, t + 1);

            if (k0 <= qs0 + 15) {
                // ---- swapped QK^T: D[kk][q], lane owns q-column ----
                f32x4 s[4];
                #pragma unroll
                for (int nt = 0; nt < 4; ++nt) {
                    const int row = nt * 16 + l15;
                    const unsigned rb = (unsigned)row * 64, sw = (unsigned)((row & 7) << 3);
                    U8 ak0, ak1;
                    ak0.u = *(const u16x8*)&Kl[c][rb + ((unsigned)(l4 * 8) ^ sw)];
                    ak1.u = *(const u16x8*)&Kl[c][rb + ((unsigned)(32 + l4 * 8) ^ sw)];
                    f32x4 z = {};
                    z = __builtin_amdgcn_mfma_f32_16x16x32_bf16(ak0.b, aq[0], z, 0, 0, 0);
                    z = __builtin_amdgcn_mfma_f32_16x16x32_bf16(ak1.b, aq[1], z, 0, 0, 0);
                    s[nt] = z;
                }

                if (k0 + KVB - 1 > qs0) {            // diagonal tile: causal mask
                    #pragma unroll
                    for (int nt = 0; nt < 4; ++nt)
                        #pragma unroll
                        for (int r = 0; r < 4; ++r)
                            if (k0 + nt * 16 + l4 * 4 + r > q) s[nt][r] = -INFINITY;
                }

                // ---- softmax with defer-max (T13) ----
                float mx = s[0][0];
                #pragma unroll
                for (int nt = 0; nt < 4; ++nt)
                    #pragma unroll
                    for (int r = 0; r < 4; ++r)
                        if (!(nt == 0 && r == 0)) mx = fmaxf(mx, s[nt][r]);
                mx = fmaxf(mx, __shfl_xor(mx, 16));
                mx = fmaxf(mx, __shfl_xor(mx, 32));

                float mn = mrun;
                if (!__all(mx - mrun <= RTHR)) {     // wave-uniform rescale path
                    mn = fmaxf(mrun, mx);
                    float fr = exp2f(mrun - mn);
                    mrun = mn;
                    lrun *= fr;
                    #pragma unroll
                    for (int r = 0; r < 4; ++r) {
                        float frr = __shfl(fr, l4 * 4 + r);
                        #pragma unroll
                        for (int nt = 0; nt < 4; ++nt) acc[nt][r] *= frr;
                    }
                }

                float p[4][4];
                float rs = 0.f;
                #pragma unroll
                for (int nt = 0; nt < 4; ++nt)
                    #pragma unroll
                    for (int r = 0; r < 4; ++r) {
                        float e = exp2f(s[nt][r] - mn);
                        p[nt][r] = e;
                        rs += e;
                    }
                rs += __shfl_xor(rs, 16);
                rs += __shfl_xor(rs, 32);
                lrun += rs;

                // ---- P (C-layout) -> swizzled per-wave LDS ----
                unsigned short* Pw = &Pl[w][0];
                const unsigned psw = (unsigned)((l15 & 7) << 3);
                #pragma unroll
                for (int nt = 0; nt < 4; ++nt) {
                    u16x4 pk;
                    pk[0] = f2bf(p[nt][0]); pk[1] = f2bf(p[nt][1]);
                    pk[2] = f2bf(p[nt][2]); pk[3] = f2bf(p[nt][3]);
                    *(u16x4*)&Pw[l15 * 64 + ((unsigned)(nt * 16 + l4 * 4) ^ psw)] = pk;
                }

                asm volatile("s_waitcnt lgkmcnt(0)" ::: "memory");
                __builtin_amdgcn_sched_barrier(0);

                // ---- PV: acc += P(16q x 64kk) @ V(64kk x 64d) ----
                U8 pa0, pa1;
                pa0.u = *(const u16x8*)&Pw[l15 * 64 + ((unsigned)(l4 * 8) ^ psw)];
                pa1.u = *(const u16x8*)&Pw[l15 * 64 + ((unsigned)(32 + l4 * 8) ^ psw)];
                #pragma unroll
                for (int nt = 0; nt < 4; ++nt) {
                    const int row = nt * 16 + l15;
                    const unsigned rb = (unsigned)row * 64, sw = (unsigned)((row & 7) << 3);
                    U8 vb0, vb1;
                    vb0.u = *(const u16x8*)&Vl[c][rb + ((unsigned)(l4 * 8) ^ sw)];
                    vb1.u = *(const u16x8*)&Vl[c][rb + ((unsigned)(32 + l4 * 8) ^ sw)];
                    acc[nt] = __builtin_amdgcn_mfma_f32_16x16x32_bf16(pa0.b, vb0.b, acc[nt], 0, 0, 0);
                    acc[nt] = __builtin_amdgcn_mfma_f32_16x16x32_bf16(pa1.b, vb1.b, acc[nt], 0, 0, 0);
                }
            }
            __syncthreads();
        }

        // ---- epilogue: O = acc / l ----
        float inv = 1.f / lrun;
        #pragma unroll
        for (int r = 0; r < 4; ++r) {
            float invr = __shfl(inv, l4 * 4 + r);
            const int qrow = qs0 + l4 * 4 + r;
            float* op = O + qbase + (size_t)qrow * DH + l15;
            #pragma unroll
            for (int nt = 0; nt < 4; ++nt)
                op[nt * 16] = acc[nt][r] * invr;
        }
        __syncthreads();
    }
}

// ---------------- fallback (round-4 kernel, used if ws too small) ----------------
#define QBLK4 128
#define KPAD 72
#define NQT4  (SLEN/QBLK4)
#define NPAIR4 (NQT4/2)

extern "C" __global__ __launch_bounds__(256)
void fa_fwd_causal(const float* __restrict__ Q, const float* __restrict__ K,
                   const float* __restrict__ V, float* __restrict__ O)
{
    const int tid  = threadIdx.x;
    const int lane = tid & 63;
    const int w    = tid >> 6;
    const int l15  = lane & 15;
    const int l4   = lane >> 4;

    const int bid  = (int)blockIdx.x;
    const int work = (bid & 7) * (NPAIR4 * NHEAD / 8) + (bid >> 3);
    const int head = work >> 4;
    const int pr   = work & (NPAIR4 - 1);
    const size_t base = (size_t)head * SLEN * DH;

    __shared__ unsigned short Kl[2][KVB * KPAD];
    __shared__ unsigned short Vt[2][DH * KPAD];
    __shared__ unsigned short Plds[4][16 * KPAD];

    const float QSC = 0.125f * 1.44269504088896340736f;
    const int krow = tid >> 2,        kc0 = (tid & 3) * 16;
    const int vd0  = (tid >> 4) * 4,  vk0 = (tid & 15) * 4;

    #pragma unroll 1
    for (int ph = 0; ph < 2; ++ph) {
        const int qt  = ph ? (NQT4 - 1 - pr) : pr;
        const int q0  = qt * QBLK4;
        const int ntl = 2 * qt + 2;
        const int qwave = q0 + w * 32;

        bf16x8 aq[2][2];
        #pragma unroll
        for (int set = 0; set < 2; ++set) {
            const int qr = q0 + w * 32 + set * 16 + l15;
            const float* qp = Q + base + (size_t)qr * DH + l4 * 8;
            #pragma unroll
            for (int ch = 0; ch < 2; ++ch) {
                f32x4 f0 = *(const f32x4*)(qp + ch * 32);
                f32x4 f1 = *(const f32x4*)(qp + ch * 32 + 4);
                U8 u;
                #pragma unroll
                for (int j = 0; j < 4; ++j) { u.u[j] = f2bf(f0[j] * QSC); u.u[4 + j] = f2bf(f1[j] * QSC); }
                aq[set][ch] = u.b;
            }
        }

        f32x4 acc[2][4] = {};
        float mrun[2] = { -INFINITY, -INFINITY };
        float lrun[2] = { 0.f, 0.f };
        f32x4 kreg[4], vreg[4];

        auto g_load = [&](int t) {
            const float* kp = K + base + (size_t)(t * KVB + krow) * DH + kc0;
            #pragma unroll
            for (int i = 0; i < 4; ++i) kreg[i] = *(const f32x4*)(kp + i * 4);
            const float* vp = V + base + (size_t)(t * KVB + vk0) * DH + vd0;
            #pragma unroll
            for (int i = 0; i < 4; ++i) vreg[i] = *(const f32x4*)(vp + (size_t)i * DH);
        };
        auto s_write = [&](int c) {
            unsigned short tmp[16];
            #pragma unroll
            for (int i = 0; i < 4; ++i)
                #pragma unroll
                for (int j = 0; j < 4; ++j) tmp[i * 4 + j] = f2bf(kreg[i][j]);
            unsigned short* kd = &Kl[c][krow * KPAD + kc0];
            *(u16x8*)kd       = *(u16x8*)&tmp[0];
            *(u16x8*)(kd + 8) = *(u16x8*)&tmp[8];
            #pragma unroll
            for (int i = 0; i < 4; ++i) {
                u16x4 pk;
                pk[0] = f2bf(vreg[0][i]); pk[1] = f2bf(vreg[1][i]);
                pk[2] = f2bf(vreg[2][i]); pk[3] = f2bf(vreg[3][i]);
                *(u16x4*)&Vt[c][(vd0 + i) * KPAD + vk0] = pk;
            }
        };

        g_load(0); s_write(0); g_load(1);
        __syncthreads();

        for (int t = 0; t < ntl; ++t) {
            const int c  = t & 1;
            const int k0 = t * KVB;
            if (t + 1 < ntl) { s_write(c ^ 1); if (t + 2 < ntl) g_load(t + 2); }

            if (k0 <= qwave + 31) {
                #pragma unroll
                for (int set = 0; set < 2; ++set) {
                    const int qs0 = qwave + set * 16;
                    if (k0 > qs0 + 15) continue;
                    const int q = qs0 + l15;

                    f32x4 s[4];
                    #pragma unroll
                    for (int nt = 0; nt < 4; ++nt) {
                        U8 ak0, ak1;
                        ak0.u = *(const u16x8*)&Kl[c][(nt*16 + l15) * KPAD + l4*8];
                        ak1.u = *(const u16x8*)&Kl[c][(nt*16 + l15) * KPAD + 32 + l4*8];
                        f32x4 z = {};
                        z = __builtin_amdgcn_mfma_f32_16x16x32_bf16(ak0.b, aq[set][0], z, 0, 0, 0);
                        z = __builtin_amdgcn_mfma_f32_16x16x32_bf16(ak1.b, aq[set][1], z, 0, 0, 0);
                        s[nt] = z;
                    }
                    if (k0 + KVB - 1 > qs0) {
                        #pragma unroll
                        for (int nt = 0; nt < 4; ++nt)
                            #pragma unroll
                            for (int r = 0; r < 4; ++r)
                                if (k0 + nt*16 + l4*4 + r > q) s[nt][r] = -INFINITY;
                    }
                    float mx = s[0][0];
                    #pragma unroll
                    for (int nt = 0; nt < 4; ++nt)
                        #pragma unroll
                        for (int r = 0; r < 4; ++r)
                            if (!(nt == 0 && r == 0)) mx = fmaxf(mx, s[nt][r]);
                    mx = fmaxf(mx, __shfl_xor(mx, 16));
                    mx = fmaxf(mx, __shfl_xor(mx, 32));
                    float mn = fmaxf(mrun[set], mx);
                    float fr = exp2f(mrun[set] - mn);
                    mrun[set] = mn;
                    float p[4][4];
                    float rs = 0.f;
                    #pragma unroll
                    for (int nt = 0; nt < 4; ++nt)
                        #pragma unroll
                        for (int r = 0; r < 4; ++r) {
                            float e = exp2f(s[nt][r] - mn);
                            p[nt][r] = e; rs += e;
                        }
                    rs += __shfl_xor(rs, 16);
                    rs += __shfl_xor(rs, 32);
                    lrun[set] = lrun[set] * fr + rs;

                    unsigned short* Pw = &Plds[w][0];
                    #pragma unroll
                    for (int nt = 0; nt < 4; ++nt) {
                        u16x4 pk;
                        pk[0] = f2bf(p[nt][0]); pk[1] = f2bf(p[nt][1]);
                        pk[2] = f2bf(p[nt][2]); pk[3] = f2bf(p[nt][3]);
                        *(u16x4*)&Pw[l15 * KPAD + nt*16 + l4*4] = pk;
                    }
                    #pragma unroll
                    for (int r = 0; r < 4; ++r) {
                        float frr = __shfl(fr, l4*4 + r);
                        #pragma unroll
                        for (int nt = 0; nt < 4; ++nt) acc[set][nt][r] *= frr;
                    }
                    asm volatile("s_waitcnt lgkmcnt(0)" ::: "memory");
                    __builtin_amdgcn_sched_barrier(0);
                    U8 pa0, pa1;
                    pa0.u = *(const u16x8*)&Pw[l15 * KPAD + l4*8];
                    pa1.u = *(const u16x8*)&Pw[l15 * KPAD + 32 + l4*8];
                    #pragma unroll
                    for (int nt = 0; nt < 4; ++nt) {
                        U8 vb0, vb1;
                        vb0.u = *(const u16x8*)&Vt[c][(nt*16 + l15) * KPAD + l4*8];
                        vb1.u = *(const u16x8*)&Vt[c][(nt*16 + l15) * KPAD + 32 + l4*8];
                        acc[set][nt] = __builtin_amdgcn_mfma_f32_16x16x32_bf16(pa0.b, vb0.b, acc[set][nt], 0, 0, 0);
                        acc[set][nt] = __builtin_amdgcn_mfma_f32_16x16x32_bf16(pa1.b, vb1.b, acc[set][nt], 0, 0, 0);
                    }
                }
            }
            __syncthreads();
        }
        #pragma unroll
        for (int set = 0; set < 2; ++set) {
            float inv = 1.f / lrun[set];
            #pragma unroll
            for (int r = 0; r < 4; ++r) {
                float invr = __shfl(inv, l4*4 + r);
                const int qrow = q0 + w*32 + set*16 + l4*4 + r;
                float* op = O + base + (size_t)qrow * DH + l15;
                #pragma unroll
                for (int nt = 0; nt < 4; ++nt)
                    op[nt*16] = acc[set][nt][r] * invr;
            }
        }
        __syncthreads();
    }
}

extern "C" void kernel_launch(void* const* d_in, const int* in_sizes, int n_in,
                              void* d_out, int out_size, void* d_ws, size_t ws_size,
                              hipStream_t stream) {
    (void)in_sizes; (void)n_in; (void)out_size;
    const float* q = (const float*)d_in[0];
    const float* k = (const float*)d_in[1];
    const float* v = (const float*)d_in[2];
    float* o = (float*)d_out;

    const size_t kv_elems = (size_t)NHEAD * 64 * KVB * DH;   // 8M elems per tensor
    const size_t need = 2 * kv_elems * sizeof(unsigned short); // 32 MB
    if (ws_size >= need) {
        unsigned short* Kb = (unsigned short*)d_ws;
        unsigned short* Vt = Kb + kv_elems;
        prep_kv<<<dim3(NHEAD * 64, 2), 512, 0, stream>>>(k, v, Kb, Vt);
        fa_fwd_v5<<<dim3(NPAIR * NHEAD), 256, 0, stream>>>(q, o, Kb, Vt);
    } else {
        fa_fwd_causal<<<dim3(NPAIR4 * NHEAD), 256, 0, stream>>>(q, k, v, o);
    }
}

// Round 6
// 154.380 us; speedup vs baseline: 2.9810x; 1.0855x over previous
//
#include <hip/hip_runtime.h>
#include <hip/hip_bf16.h>
#include <math.h>

#define SLEN 4096
#define DH   64
#define KVB  64
#define NHEAD 32

typedef float  f32x4 __attribute__((ext_vector_type(4)));
typedef short  bf16x8 __attribute__((ext_vector_type(8)));
typedef unsigned short u16x8 __attribute__((ext_vector_type(8)));
typedef unsigned short u16x4 __attribute__((ext_vector_type(4)));
union U8 { u16x8 u; bf16x8 b; };

__device__ inline unsigned short f2bf(float f) {
    return __builtin_bit_cast(unsigned short, __float2bfloat16(f));
}
__device__ inline float max3f(float a, float b, float c) {
    return fmaxf(fmaxf(a, b), c);   // clang fuses to v_max3_f32
}

__device__ inline void gload16(const unsigned short* g, unsigned short* l) {
    __builtin_amdgcn_global_load_lds(
        (const __attribute__((address_space(1))) void*)g,
        (__attribute__((address_space(3))) void*)l, 16, 0, 0);
}

// ---------------- pre-pass: f32 K,V -> bf16 swizzled tile layout in ws ----------
// Tile layout (4096 bf16 elems): elem index = row*64 + (d ^ ((row&7)<<3)).
// K tiles: row = kv index, d = head dim. V tiles: row = head dim, d = kv (transposed).
extern "C" __global__ __launch_bounds__(512)
void prep_kv(const float* __restrict__ K, const float* __restrict__ V,
             unsigned short* __restrict__ Kb, unsigned short* __restrict__ Vt)
{
    const int tile = blockIdx.x & 63;
    const int head = blockIdx.x >> 6;
    const size_t gbase = (size_t)head * SLEN * DH + (size_t)tile * KVB * DH;
    const size_t tbase = ((size_t)head * 64 + tile) * (KVB * DH);
    const int tid = threadIdx.x;
    if (blockIdx.y == 0) {
        const int row = tid >> 3, d0 = (tid & 7) * 8;
        const float* src = K + gbase + (size_t)row * DH + d0;
        f32x4 a = *(const f32x4*)src, b = *(const f32x4*)(src + 4);
        u16x8 o;
        #pragma unroll
        for (int j = 0; j < 4; ++j) { o[j] = f2bf(a[j]); o[4 + j] = f2bf(b[j]); }
        *(u16x8*)&Kb[tbase + row * 64 + ((unsigned)d0 ^ ((row & 7) << 3))] = o;
    } else {
        const int kk = tid & 63, d0 = (tid >> 6) * 8;
        const float* src = V + gbase + (size_t)kk * DH + d0;
        f32x4 a = *(const f32x4*)src, b = *(const f32x4*)(src + 4);
        #pragma unroll
        for (int j = 0; j < 8; ++j) {
            const int d = d0 + j;
            const float x = (j < 4) ? a[j] : b[j - 4];
            Vt[tbase + d * 64 + ((unsigned)kk ^ ((d & 7) << 3))] = f2bf(x);
        }
    }
}

// ---------------- main kernel: QBLK=64, global_load_lds staging ----------------
#define NQT   (SLEN / KVB)   // 64 q-tiles of 64
#define NPAIR (NQT / 2)      // 32
#define RTHR  10.0f          // defer-max threshold, exp2 domain

extern "C" __global__ __launch_bounds__(256, 4)
void fa_fwd_v6(const float* __restrict__ Q, float* __restrict__ O,
               const unsigned short* __restrict__ Kb,
               const unsigned short* __restrict__ Vt)
{
    const int tid  = threadIdx.x;
    const int lane = tid & 63;
    const int w    = tid >> 6;
    const int l15  = lane & 15;
    const int l4   = lane >> 4;

    // 1024 blocks, XCD-chunked swizzle (1024%8==0 -> bijective)
    const int bid  = (int)blockIdx.x;
    const int work = (bid & 7) * (NPAIR * NHEAD / 8) + (bid >> 3);
    const int head = work >> 5;
    const int pr   = work & (NPAIR - 1);
    const size_t qbase  = (size_t)head * SLEN * DH;
    const size_t kvbase = (size_t)head * 64 * (KVB * DH);

    __shared__ __align__(16) unsigned short Kl[2][KVB * DH];
    __shared__ __align__(16) unsigned short Vl[2][DH * KVB];
    __shared__ __align__(16) unsigned short Pl[4][16 * 64];

    const float QSC = 0.125f * 1.44269504088896340736f;

    // bf16 ones B-fragment for the row-sum MFMA
    U8 ones;
    #pragma unroll
    for (int j = 0; j < 8; ++j) ones.u[j] = 0x3F80;

    #pragma unroll 1
    for (int ph = 0; ph < 2; ++ph) {
        const int qt  = ph ? (NQT - 1 - pr) : pr;
        const int q0  = qt * KVB;
        const int ntl = qt + 1;
        const int qs0 = q0 + w * 16;
        const int q   = qs0 + l15;

        const unsigned short* ksrc = Kb + kvbase;
        const unsigned short* vsrc = Vt + kvbase;
        auto stage = [&](int c, int t) {
            const size_t toff = (size_t)t * (KVB * DH);
            const int ib = w * 2;
            gload16(ksrc + toff + ib * 512 + lane * 8,       &Kl[c][ib * 512]);
            gload16(ksrc + toff + (ib + 1) * 512 + lane * 8, &Kl[c][(ib + 1) * 512]);
            gload16(vsrc + toff + ib * 512 + lane * 8,       &Vl[c][ib * 512]);
            gload16(vsrc + toff + (ib + 1) * 512 + lane * 8, &Vl[c][(ib + 1) * 512]);
        };

        stage(0, 0);

        // Q fragment (B-operand: lane holds Q[q=l15][d-run]), scaled
        bf16x8 aq[2];
        {
            const float* qp = Q + qbase + (size_t)q * DH + l4 * 8;
            #pragma unroll
            for (int ch = 0; ch < 2; ++ch) {
                f32x4 f0 = *(const f32x4*)(qp + ch * 32);
                f32x4 f1 = *(const f32x4*)(qp + ch * 32 + 4);
                U8 u;
                #pragma unroll
                for (int j = 0; j < 4; ++j) { u.u[j] = f2bf(f0[j] * QSC); u.u[4 + j] = f2bf(f1[j] * QSC); }
                aq[ch] = u.b;
            }
        }

        f32x4 acc[4] = {};
        f32x4 lrow = {};                 // row-layout softmax denominators
        float mrun  = 0.f;               // running max, exp2 domain, col layout (q=l15)
        float negmn = 0.f;               // -mrun, used as QK^T accumulator seed

        __syncthreads();

        for (int t = 0; t < ntl; ++t) {
            const int c  = t & 1;
            const int k0 = t * KVB;
            if (t + 1 < ntl) stage(c ^ 1, t + 1);

            {
                // ---- swapped QK^T seeded with -mrun: s' = K Q^T - mrun ----
                f32x4 s[4];
                #pragma unroll
                for (int nt = 0; nt < 4; ++nt) {
                    const int row = nt * 16 + l15;
                    const unsigned rb = (unsigned)row * 64, sw = (unsigned)((row & 7) << 3);
                    U8 ak0, ak1;
                    ak0.u = *(const u16x8*)&Kl[c][rb + ((unsigned)(l4 * 8) ^ sw)];
                    ak1.u = *(const u16x8*)&Kl[c][rb + ((unsigned)(32 + l4 * 8) ^ sw)];
                    f32x4 z = { negmn, negmn, negmn, negmn };
                    z = __builtin_amdgcn_mfma_f32_16x16x32_bf16(ak0.b, aq[0], z, 0, 0, 0);
                    z = __builtin_amdgcn_mfma_f32_16x16x32_bf16(ak1.b, aq[1], z, 0, 0, 0);
                    s[nt] = z;
                }

                if (k0 + KVB - 1 > qs0) {            // diagonal tile: causal mask
                    #pragma unroll
                    for (int nt = 0; nt < 4; ++nt)
                        #pragma unroll
                        for (int r = 0; r < 4; ++r)
                            if (k0 + nt * 16 + l4 * 4 + r > q) s[nt][r] = -INFINITY;
                }

                // ---- tree max (v_max3 fusion) ----
                float t0 = max3f(s[0][0], s[0][1], s[0][2]);
                float t1 = max3f(s[0][3], s[1][0], s[1][1]);
                float t2 = max3f(s[1][2], s[1][3], s[2][0]);
                float t3 = max3f(s[2][1], s[2][2], s[2][3]);
                float t4 = max3f(s[3][0], s[3][1], s[3][2]);
                float mx = fmaxf(max3f(t0, t1, t2), max3f(t3, t4, s[3][3]));
                mx = fmaxf(mx, __shfl_xor(mx, 16));
                mx = fmaxf(mx, __shfl_xor(mx, 32));

                if (!__all(mx <= RTHR)) {            // rare rescale path
                    float d  = fmaxf(mx, 0.f);
                    float fr = exp2f(-d);
                    mrun += d;
                    negmn = -mrun;
                    #pragma unroll
                    for (int r = 0; r < 4; ++r) {
                        float frr = __shfl(fr, l4 * 4 + r);
                        lrow[r] *= frr;
                        #pragma unroll
                        for (int nt = 0; nt < 4; ++nt) acc[nt][r] *= frr;
                    }
                    #pragma unroll
                    for (int nt = 0; nt < 4; ++nt)
                        #pragma unroll
                        for (int r = 0; r < 4; ++r) s[nt][r] -= d;
                }

                // ---- P = exp2(s'), pack bf16, store to swizzled per-wave LDS ----
                unsigned short* Pw = &Pl[w][0];
                const unsigned psw = (unsigned)((l15 & 7) << 3);
                #pragma unroll
                for (int nt = 0; nt < 4; ++nt) {
                    u16x4 pk;
                    pk[0] = f2bf(exp2f(s[nt][0]));
                    pk[1] = f2bf(exp2f(s[nt][1]));
                    pk[2] = f2bf(exp2f(s[nt][2]));
                    pk[3] = f2bf(exp2f(s[nt][3]));
                    *(u16x4*)&Pw[l15 * 64 + ((unsigned)(nt * 16 + l4 * 4) ^ psw)] = pk;
                }

                asm volatile("s_waitcnt lgkmcnt(0)" ::: "memory");
                __builtin_amdgcn_sched_barrier(0);

                // ---- PV + row-sum: acc += P @ V ; lrow += P @ ones ----
                U8 pa0, pa1;
                pa0.u = *(const u16x8*)&Pw[l15 * 64 + ((unsigned)(l4 * 8) ^ psw)];
                pa1.u = *(const u16x8*)&Pw[l15 * 64 + ((unsigned)(32 + l4 * 8) ^ psw)];
                lrow = __builtin_amdgcn_mfma_f32_16x16x32_bf16(pa0.b, ones.b, lrow, 0, 0, 0);
                lrow = __builtin_amdgcn_mfma_f32_16x16x32_bf16(pa1.b, ones.b, lrow, 0, 0, 0);
                #pragma unroll
                for (int nt = 0; nt < 4; ++nt) {
                    const int row = nt * 16 + l15;
                    const unsigned rb = (unsigned)row * 64, sw = (unsigned)((row & 7) << 3);
                    U8 vb0, vb1;
                    vb0.u = *(const u16x8*)&Vl[c][rb + ((unsigned)(l4 * 8) ^ sw)];
                    vb1.u = *(const u16x8*)&Vl[c][rb + ((unsigned)(32 + l4 * 8) ^ sw)];
                    acc[nt] = __builtin_amdgcn_mfma_f32_16x16x32_bf16(pa0.b, vb0.b, acc[nt], 0, 0, 0);
                    acc[nt] = __builtin_amdgcn_mfma_f32_16x16x32_bf16(pa1.b, vb1.b, acc[nt], 0, 0, 0);
                }
            }
            __syncthreads();
        }

        // ---- epilogue: O = acc / lrow (all in row layout, no shuffles) ----
        #pragma unroll
        for (int r = 0; r < 4; ++r) {
            float invr = 1.f / lrow[r];
            const int qrow = qs0 + l4 * 4 + r;
            float* op = O + qbase + (size_t)qrow * DH + l15;
            #pragma unroll
            for (int nt = 0; nt < 4; ++nt)
                op[nt * 16] = acc[nt][r] * invr;
        }
        __syncthreads();
    }
}

// ---------------- fallback (round-4 kernel, used if ws too small) ----------------
#define QBLK4 128
#define KPAD 72
#define NQT4  (SLEN/QBLK4)
#define NPAIR4 (NQT4/2)

extern "C" __global__ __launch_bounds__(256)
void fa_fwd_causal(const float* __restrict__ Q, const float* __restrict__ K,
                   const float* __restrict__ V, float* __restrict__ O)
{
    const int tid  = threadIdx.x;
    const int lane = tid & 63;
    const int w    = tid >> 6;
    const int l15  = lane & 15;
    const int l4   = lane >> 4;

    const int bid  = (int)blockIdx.x;
    const int work = (bid & 7) * (NPAIR4 * NHEAD / 8) + (bid >> 3);
    const int head = work >> 4;
    const int pr   = work & (NPAIR4 - 1);
    const size_t base = (size_t)head * SLEN * DH;

    __shared__ unsigned short Kl[2][KVB * KPAD];
    __shared__ unsigned short Vt[2][DH * KPAD];
    __shared__ unsigned short Plds[4][16 * KPAD];

    const float QSC = 0.125f * 1.44269504088896340736f;
    const int krow = tid >> 2,        kc0 = (tid & 3) * 16;
    const int vd0  = (tid >> 4) * 4,  vk0 = (tid & 15) * 4;

    #pragma unroll 1
    for (int ph = 0; ph < 2; ++ph) {
        const int qt  = ph ? (NQT4 - 1 - pr) : pr;
        const int q0  = qt * QBLK4;
        const int ntl = 2 * qt + 2;
        const int qwave = q0 + w * 32;

        bf16x8 aq[2][2];
        #pragma unroll
        for (int set = 0; set < 2; ++set) {
            const int qr = q0 + w * 32 + set * 16 + l15;
            const float* qp = Q + base + (size_t)qr * DH + l4 * 8;
            #pragma unroll
            for (int ch = 0; ch < 2; ++ch) {
                f32x4 f0 = *(const f32x4*)(qp + ch * 32);
                f32x4 f1 = *(const f32x4*)(qp + ch * 32 + 4);
                U8 u;
                #pragma unroll
                for (int j = 0; j < 4; ++j) { u.u[j] = f2bf(f0[j] * QSC); u.u[4 + j] = f2bf(f1[j] * QSC); }
                aq[set][ch] = u.b;
            }
        }

        f32x4 acc[2][4] = {};
        float mrun[2] = { -INFINITY, -INFINITY };
        float lrun[2] = { 0.f, 0.f };
        f32x4 kreg[4], vreg[4];

        auto g_load = [&](int t) {
            const float* kp = K + base + (size_t)(t * KVB + krow) * DH + kc0;
            #pragma unroll
            for (int i = 0; i < 4; ++i) kreg[i] = *(const f32x4*)(kp + i * 4);
            const float* vp = V + base + (size_t)(t * KVB + vk0) * DH + vd0;
            #pragma unroll
            for (int i = 0; i < 4; ++i) vreg[i] = *(const f32x4*)(vp + (size_t)i * DH);
        };
        auto s_write = [&](int c) {
            unsigned short tmp[16];
            #pragma unroll
            for (int i = 0; i < 4; ++i)
                #pragma unroll
                for (int j = 0; j < 4; ++j) tmp[i * 4 + j] = f2bf(kreg[i][j]);
            unsigned short* kd = &Kl[c][krow * KPAD + kc0];
            *(u16x8*)kd       = *(u16x8*)&tmp[0];
            *(u16x8*)(kd + 8) = *(u16x8*)&tmp[8];
            #pragma unroll
            for (int i = 0; i < 4; ++i) {
                u16x4 pk;
                pk[0] = f2bf(vreg[0][i]); pk[1] = f2bf(vreg[1][i]);
                pk[2] = f2bf(vreg[2][i]); pk[3] = f2bf(vreg[3][i]);
                *(u16x4*)&Vt[c][(vd0 + i) * KPAD + vk0] = pk;
            }
        };

        g_load(0); s_write(0); g_load(1);
        __syncthreads();

        for (int t = 0; t < ntl; ++t) {
            const int c  = t & 1;
            const int k0 = t * KVB;
            if (t + 1 < ntl) { s_write(c ^ 1); if (t + 2 < ntl) g_load(t + 2); }

            if (k0 <= qwave + 31) {
                #pragma unroll
                for (int set = 0; set < 2; ++set) {
                    const int qs0 = qwave + set * 16;
                    if (k0 > qs0 + 15) continue;
                    const int q = qs0 + l15;

                    f32x4 s[4];
                    #pragma unroll
                    for (int nt = 0; nt < 4; ++nt) {
                        U8 ak0, ak1;
                        ak0.u = *(const u16x8*)&Kl[c][(nt*16 + l15) * KPAD + l4*8];
                        ak1.u = *(const u16x8*)&Kl[c][(nt*16 + l15) * KPAD + 32 + l4*8];
                        f32x4 z = {};
                        z = __builtin_amdgcn_mfma_f32_16x16x32_bf16(ak0.b, aq[set][0], z, 0, 0, 0);
                        z = __builtin_amdgcn_mfma_f32_16x16x32_bf16(ak1.b, aq[set][1], z, 0, 0, 0);
                        s[nt] = z;
                    }
                    if (k0 + KVB - 1 > qs0) {
                        #pragma unroll
                        for (int nt = 0; nt < 4; ++nt)
                            #pragma unroll
                            for (int r = 0; r < 4; ++r)
                                if (k0 + nt*16 + l4*4 + r > q) s[nt][r] = -INFINITY;
                    }
                    float mx = s[0][0];
                    #pragma unroll
                    for (int nt = 0; nt < 4; ++nt)
                        #pragma unroll
                        for (int r = 0; r < 4; ++r)
                            if (!(nt == 0 && r == 0)) mx = fmaxf(mx, s[nt][r]);
                    mx = fmaxf(mx, __shfl_xor(mx, 16));
                    mx = fmaxf(mx, __shfl_xor(mx, 32));
                    float mn = fmaxf(mrun[set], mx);
                    float fr = exp2f(mrun[set] - mn);
                    mrun[set] = mn;
                    float p[4][4];
                    float rs = 0.f;
                    #pragma unroll
                    for (int nt = 0; nt < 4; ++nt)
                        #pragma unroll
                        for (int r = 0; r < 4; ++r) {
                            float e = exp2f(s[nt][r] - mn);
                            p[nt][r] = e; rs += e;
                        }
                    rs += __shfl_xor(rs, 16);
                    rs += __shfl_xor(rs, 32);
                    lrun[set] = lrun[set] * fr + rs;

                    unsigned short* Pw = &Plds[w][0];
                    #pragma unroll
                    for (int nt = 0; nt < 4; ++nt) {
                        u16x4 pk;
                        pk[0] = f2bf(p[nt][0]); pk[1] = f2bf(p[nt][1]);
                        pk[2] = f2bf(p[nt][2]); pk[3] = f2bf(p[nt][3]);
                        *(u16x4*)&Pw[l15 * KPAD + nt*16 + l4*4] = pk;
                    }
                    #pragma unroll
                    for (int r = 0; r < 4; ++r) {
                        float frr = __shfl(fr, l4*4 + r);
                        #pragma unroll
                        for (int nt = 0; nt < 4; ++nt) acc[set][nt][r] *= frr;
                    }
                    asm volatile("s_waitcnt lgkmcnt(0)" ::: "memory");
                    __builtin_amdgcn_sched_barrier(0);
                    U8 pa0, pa1;
                    pa0.u = *(const u16x8*)&Pw[l15 * KPAD + l4*8];
                    pa1.u = *(const u16x8*)&Pw[l15 * KPAD + 32 + l4*8];
                    #pragma unroll
                    for (int nt = 0; nt < 4; ++nt) {
                        U8 vb0, vb1;
                        vb0.u = *(const u16x8*)&Vt[c][(nt*16 + l15) * KPAD + l4*8];
                        vb1.u = *(const u16x8*)&Vt[c][(nt*16 + l15) * KPAD + 32 + l4*8];
                        acc[set][nt] = __builtin_amdgcn_mfma_f32_16x16x32_bf16(pa0.b, vb0.b, acc[set][nt], 0, 0, 0);
                        acc[set][nt] = __builtin_amdgcn_mfma_f32_16x16x32_bf16(pa1.b, vb1.b, acc[set][nt], 0, 0, 0);
                    }
                }
            }
            __syncthreads();
        }
        #pragma unroll
        for (int set = 0; set < 2; ++set) {
            float inv = 1.f / lrun[set];
            #pragma unroll
            for (int r = 0; r < 4; ++r) {
                float invr = __shfl(inv, l4*4 + r);
                const int qrow = q0 + w*32 + set*16 + l4*4 + r;
                float* op = O + base + (size_t)qrow * DH + l15;
                #pragma unroll
                for (int nt = 0; nt < 4; ++nt)
                    op[nt*16] = acc[set][nt][r] * invr;
            }
        }
        __syncthreads();
    }
}

extern "C" void kernel_launch(void* const* d_in, const int* in_sizes, int n_in,
                              void* d_out, int out_size, void* d_ws, size_t ws_size,
                              hipStream_t stream) {
    (void)in_sizes; (void)n_in; (void)out_size;
    const float* q = (const float*)d_in[0];
    const float* k = (const float*)d_in[1];
    const float* v = (const float*)d_in[2];
    float* o = (float*)d_out;

    const size_t kv_elems = (size_t)NHEAD * 64 * KVB * DH;
    const size_t need = 2 * kv_elems * sizeof(unsigned short);
    if (ws_size >= need) {
        unsigned short* Kb = (unsigned short*)d_ws;
        unsigned short* Vt = Kb + kv_elems;
        prep_kv<<<dim3(NHEAD * 64, 2), 512, 0, stream>>>(k, v, Kb, Vt);
        fa_fwd_v6<<<dim3(NPAIR * NHEAD), 256, 0, stream>>>(q, o, Kb, Vt);
    } else {
        fa_fwd_causal<<<dim3(NPAIR4 * NHEAD), 256, 0, stream>>>(q, k, v, o);
    }
}